// Round 3
// baseline (1009.250 us; speedup 1.0000x reference)
//
#include <hip/hip_runtime.h>

// MoE top-2: N=8192, D=1024, E=8, DFF=4096. FP32 storage, bf16 MFMA internals.
// R2 lesson: 128^2 tiles are L3-BW-bound on staging re-fetch (~1 GB/dispatch at
//   ~5.7 TB/s); schedule tweaks moved nothing because bytes didn't change.
// R3: 256^2 tiles (8 waves, 512 thr, 128 KiB LDS dbuf, counted vmcnt(8) pipeline
//   — m230-V0 structure) halve panel re-reads for BOTH gemms; device-built
//   m-tile table compacts the grid (actives first, no trickle); XCD-chunked
//   block swizzle co-locates blocks sharing an A-panel on one XCD L2.

#define N_TOK 8192
#define DIM   1024
#define NE    8
#define DFF   4096
#define BM 256
#define BN 256
#define BK 64
#define QE 4   // experts per rotating weight-quad
#define KS2 2  // split-K factor for gemm2
#define NIT1 (DIM / BK)          // 16 K-iters, gemm1
#define NIT2 (DFF / KS2 / BK)    // 32 K-iters, gemm2

typedef unsigned short u16;
typedef short bf16x8 __attribute__((ext_vector_type(8)));
typedef float f32x4  __attribute__((ext_vector_type(4)));

// ---- workspace offsets (bytes) ----
#define TOKE_OFF   0u            // int[8192]
#define TOKW_OFF   32768u        // float[8192]
#define TLIST_OFF  65536u        // int[16384]
#define WLIST_OFF  131072u       // float[16384]
#define COUNTS_OFF 196608u       // int[8]
#define BASEP_OFF  196672u       // int[8]
#define CURSOR_OFF 196736u       // int[8]
#define QTAB_OFF   197120u       // int[2][80]: per-quad m-tile table
#define XB_OFF     1048576u      // 16 MiB: bf16 x [8192][1024]
#define H_OFF      17825792u     // 128 MiB: bf16 H [16384][4096]
#define WT_OFF     152043520u    // 32 MiB: rotating bf16 transposed weight quad

__device__ __forceinline__ float bf2f(u16 h) {
    return __uint_as_float(((unsigned)h) << 16);
}
__device__ __forceinline__ u16 f2bf(float f) {
    unsigned u = __float_as_uint(f);
    unsigned r = u + 0x7FFFu + ((u >> 16) & 1u);   // RNE
    return (u16)(r >> 16);
}

#define GLL16(g, l)                                                             \
    __builtin_amdgcn_global_load_lds(                                           \
        (const __attribute__((address_space(1))) unsigned int*)(g),             \
        (__attribute__((address_space(3))) unsigned int*)(l), 16, 0, 0)

// ------ convert+transpose: in fp32 [z][R][C] -> out bf16 [z][C][R] --------
__global__ __launch_bounds__(256) void convtrans(
        const float* __restrict__ in, u16* __restrict__ out, int R, int C) {
    __shared__ float t[32][33];
    int z = blockIdx.z;
    const float* src = in  + (size_t)z * R * C;
    u16*         dst = out + (size_t)z * R * C;
    int c0 = blockIdx.x * 32, r0 = blockIdx.y * 32;
    int tx = threadIdx.x & 7, ty = threadIdx.x >> 3;   // 8 x 32
    float4 v = *(const float4*)&src[(size_t)(r0 + ty) * C + c0 + tx * 4];
    t[tx * 4 + 0][ty] = v.x;  t[tx * 4 + 1][ty] = v.y;
    t[tx * 4 + 2][ty] = v.z;  t[tx * 4 + 3][ty] = v.w;
    __syncthreads();
    ushort4 o;
    o.x = f2bf(t[ty][tx * 4 + 0]);  o.y = f2bf(t[ty][tx * 4 + 1]);
    o.z = f2bf(t[ty][tx * 4 + 2]);  o.w = f2bf(t[ty][tx * 4 + 3]);
    *(ushort4*)&dst[(size_t)(c0 + ty) * R + r0 + tx * 4] = o;
}

// ------ gate: 256 thr/block, 8 tokens/wave; fuses x fp32->bf16 conversion --
__global__ __launch_bounds__(256) void gate_kernel(
        const float* __restrict__ x, const float* __restrict__ gw,
        u16* __restrict__ xb, int* __restrict__ tok_e, float* __restrict__ tok_w,
        int* __restrict__ counts) {
    __shared__ float gsm[NE * DIM];        // [e][d], 32 KiB
    __shared__ int hcnt[NE];
    int tid = threadIdx.x;
    if (tid < NE) hcnt[tid] = 0;
    for (int i = tid; i < NE * DIM; i += 256) {
        int d = i >> 3, e = i & 7;         // gw is [d][e]
        gsm[e * DIM + d] = gw[i];
    }
    __syncthreads();
    int lane = tid & 63, wid = tid >> 6;
    int t0 = blockIdx.x * 32 + wid * 8;
    for (int tt = 0; tt < 8; ++tt) {
        int t = t0 + tt;
        const float4* xr  = (const float4*)(x  + (size_t)t * DIM);
        ushort4*      xbr = (ushort4*)(xb + (size_t)t * DIM);
        float acc[NE];
#pragma unroll
        for (int e = 0; e < NE; ++e) acc[e] = 0.f;
#pragma unroll
        for (int j = 0; j < 4; ++j) {
            float4 xv = xr[j * 64 + lane];
            ushort4 o;
            o.x = f2bf(xv.x); o.y = f2bf(xv.y); o.z = f2bf(xv.z); o.w = f2bf(xv.w);
            xbr[j * 64 + lane] = o;
            int dbase = (j * 64 + lane) * 4;
#pragma unroll
            for (int e = 0; e < NE; ++e) {
                float4 g = *(const float4*)&gsm[e * DIM + dbase];
                acc[e] += xv.x * g.x + xv.y * g.y + xv.z * g.z + xv.w * g.w;
            }
        }
#pragma unroll
        for (int off = 32; off > 0; off >>= 1) {
#pragma unroll
            for (int e = 0; e < NE; ++e) acc[e] += __shfl_xor(acc[e], off, 64);
        }
        if (lane == 0) {
            int a = 0;
#pragma unroll
            for (int e = 1; e < NE; ++e) if (acc[e] > acc[a]) a = e;   // ties -> lowest
            int b = (a == 0) ? 1 : 0;
#pragma unroll
            for (int e = 0; e < NE; ++e) if (e != a && acc[e] > acc[b]) b = e;
            float wa = 1.f / (1.f + __expf(acc[b] - acc[a]));
            tok_e[t] = (a << 3) | b;
            tok_w[t] = wa;
            atomicAdd(&hcnt[a], 1);
            atomicAdd(&hcnt[b], 1);
        }
    }
    __syncthreads();
    if (tid < NE) atomicAdd(&counts[tid], hcnt[tid]);
}

// scan + build per-quad m-tile tables: qtab[q*80] = n_tiles; entries pack
// (expert<<20)|row0 so gemm blocks decode their tile without searching.
__global__ void scan_kernel(const int* __restrict__ counts, int* __restrict__ basep,
                            int* __restrict__ cursor, int* __restrict__ qtab) {
    if (threadIdx.x == 0) {
        int s = 0;
        for (int e = 0; e < NE; ++e) { basep[e] = s; s += counts[e]; cursor[e] = 0; }
        for (int q = 0; q < 2; ++q) {
            int n = 0;
            for (int le = 0; le < QE; ++le) {
                int e = q * QE + le;
                int c = counts[e];
                for (int r0 = 0; r0 < c; r0 += BM) {
                    qtab[q * 80 + 1 + n] = (e << 20) | r0;
                    ++n;
                }
            }
            qtab[q * 80] = n;
        }
    }
}

__global__ void assign_kernel(const int* __restrict__ tok_e, const float* __restrict__ tok_w,
                              const int* __restrict__ basep, int* __restrict__ cursor,
                              int* __restrict__ tlist, float* __restrict__ wlist) {
    int t = blockIdx.x * 256 + threadIdx.x;
    if (t >= N_TOK) return;
    int ee = tok_e[t];
    int a = ee >> 3, b = ee & 7;
    float wa = tok_w[t];
    int pa = atomicAdd(&cursor[a], 1);
    int sa = basep[a] + pa;
    tlist[sa] = t;  wlist[sa] = wa;
    int pb = atomicAdd(&cursor[b], 1);
    int sb = basep[b] + pb;
    tlist[sb] = t;  wlist[sb] = 1.f - wa;
}

// ---------------- gemm1+SiLU: H[slot][f] = silu(xb[tok] @ w1[e]) ----------
// 256x256 tile, 8 waves (2M x 4N), LDS dbuf 128 KiB, counted vmcnt pipeline.
// grid = 1152 (72 g-slots x 16 nt); XCD-chunk swizzle in groups of 128 so the
// 16 nt-blocks of one A-panel land on one XCD.
__global__ __launch_bounds__(512, 2) void gemm1_silu(
        const u16* __restrict__ xb, const u16* __restrict__ w1t,
        const int* __restrict__ tlist, const int* __restrict__ counts,
        const int* __restrict__ basep, const int* __restrict__ qtab,
        u16* __restrict__ H, int ebase) {
    int bx = blockIdx.x;
    int work = (bx & ~127) | ((bx & 7) << 4) | ((bx & 127) >> 3);
    int g = work >> 4, nt = work & 15;
    const int* tab = qtab + (ebase >> 2) * 80;
    if (g >= tab[0]) return;
    int pk = tab[1 + g];
    int e = pk >> 20, row0 = pk & 0xFFFFF;
    int le = e - ebase;
    int cnt = counts[e];
    int nv = cnt - row0; if (nv > BM) nv = BM;
    int gb = basep[e] + row0;

    __shared__ __align__(16) u16 As[2][BM * BK];   // 2 x 32 KiB
    __shared__ __align__(16) u16 Bs[2][BN * BK];   // 2 x 32 KiB

    int tid = threadIdx.x;
    int lane = tid & 63, wid = tid >> 6;
    int wm = (wid & 1) * 128, wn = (wid >> 1) * 64;

    // staging: 2048 chunks of 16 B per tile; thread stages 4 A + 4 B chunks.
    // LDS dest linear (wave-uniform base + lane*16); XOR swizzle pre-applied
    // to the GLOBAL source chunk so fragment reads are conflict-free.
    const u16* ga[4]; const u16* gbp[4]; int loff[4];
#pragma unroll
    for (int i = 0; i < 4; ++i) {
        int cidx = wid * 256 + i * 64 + lane;   // 0..2047
        int row = cidx >> 3;
        int cg  = (cidx & 7) ^ (row & 7);
        int ra  = (row < nv) ? row : 0;
        ga[i]  = xb + (size_t)tlist[gb + ra] * DIM + cg * 8;
        gbp[i] = w1t + ((size_t)le * DFF + (size_t)nt * BN + row) * DIM + cg * 8;
        loff[i] = wid * 2048 + i * 512;         // u16 elements
    }

    f32x4 acc[8][4];
#pragma unroll
    for (int i = 0; i < 8; ++i)
#pragma unroll
        for (int j = 0; j < 4; ++j) acc[i][j] = (f32x4){0.f, 0.f, 0.f, 0.f};

#define STAGE1(buf, kk)                                                         \
    do {                                                                        \
        _Pragma("unroll")                                                       \
        for (int i = 0; i < 4; ++i) {                                           \
            GLL16(ga[i] + (kk), &As[buf][loff[i]]);                             \
            GLL16(gbp[i] + (kk), &Bs[buf][loff[i]]);                            \
        }                                                                       \
    } while (0)

#define COMPUTE1(buf)                                                           \
    do {                                                                        \
        _Pragma("unroll")                                                       \
        for (int ks = 0; ks < 2; ++ks) {                                        \
            int kc = ks * 4 + (lane >> 4);                                      \
            bf16x8 af[8], bfr[4];                                               \
            _Pragma("unroll")                                                   \
            for (int mi = 0; mi < 8; ++mi) {                                    \
                int r = wm + mi * 16 + (lane & 15);                             \
                af[mi] = *(const bf16x8*)&As[buf][(r * 8 + (kc ^ (r & 7))) * 8];\
            }                                                                   \
            _Pragma("unroll")                                                   \
            for (int ni = 0; ni < 4; ++ni) {                                    \
                int r = wn + ni * 16 + (lane & 15);                             \
                bfr[ni] = *(const bf16x8*)&Bs[buf][(r * 8 + (kc ^ (r & 7))) * 8];\
            }                                                                   \
            _Pragma("unroll")                                                   \
            for (int mi = 0; mi < 8; ++mi)                                      \
                _Pragma("unroll")                                               \
                for (int ni = 0; ni < 4; ++ni)                                  \
                    acc[mi][ni] = __builtin_amdgcn_mfma_f32_16x16x32_bf16(      \
                        af[mi], bfr[ni], acc[mi][ni], 0, 0, 0);                 \
        }                                                                       \
    } while (0)

    STAGE1(0, 0);
    int cur = 0;
    for (int t = 0; t < NIT1 - 1; ++t) {
        STAGE1(cur ^ 1, (t + 1) * BK);
        asm volatile("s_waitcnt vmcnt(8)" ::: "memory");
        __builtin_amdgcn_s_barrier();
        __builtin_amdgcn_sched_barrier(0);
        COMPUTE1(cur);
        __builtin_amdgcn_s_barrier();
        cur ^= 1;
    }
    asm volatile("s_waitcnt vmcnt(0)" ::: "memory");
    __builtin_amdgcn_s_barrier();
    __builtin_amdgcn_sched_barrier(0);
    COMPUTE1(cur);

    // epilogue: SiLU -> bf16 -> H. C layout: col=lane&15, row=(lane>>4)*4+r.
#pragma unroll
    for (int mi = 0; mi < 8; ++mi) {
#pragma unroll
        for (int r = 0; r < 4; ++r) {
            int row = wm + mi * 16 + (lane >> 4) * 4 + r;
            if (row < nv) {
                size_t ho = (size_t)(gb + row) * DFF + nt * BN + wn + (lane & 15);
#pragma unroll
                for (int ni = 0; ni < 4; ++ni) {
                    float v = acc[mi][ni][r];
                    H[ho + ni * 16] = f2bf(v / (1.f + __expf(-v)));
                }
            }
        }
    }
#undef STAGE1
#undef COMPUTE1
}

// ---- gemm2 + combine: y[tok][d] += w * (H[slot] @ w2[e]), fp32 atomics ----
// 256x256 tile, split-K (KS2=2). grid = 576 (72 g x 4 nt x 2 ksp);
// XCD-chunk swizzle in groups of 64.
__global__ __launch_bounds__(512, 2) void gemm2_combine(
        const u16* __restrict__ H, const u16* __restrict__ w2t,
        const int* __restrict__ tlist, const float* __restrict__ wlist,
        const int* __restrict__ counts, const int* __restrict__ basep,
        const int* __restrict__ qtab, float* __restrict__ y, int ebase) {
    int bx = blockIdx.x;
    int work = (bx & ~63) | ((bx & 7) << 3) | ((bx & 63) >> 3);
    int g = work >> 3, nt = (work >> 1) & 3, ksp = work & 1;
    const int* tab = qtab + (ebase >> 2) * 80;
    if (g >= tab[0]) return;
    int pk = tab[1 + g];
    int e = pk >> 20, row0 = pk & 0xFFFFF;
    int le = e - ebase;
    int cnt = counts[e];
    int nv = cnt - row0; if (nv > BM) nv = BM;
    int gb = basep[e] + row0;

    __shared__ __align__(16) u16 As[2][BM * BK];
    __shared__ __align__(16) u16 Bs[2][BN * BK];

    int tid = threadIdx.x;
    int lane = tid & 63, wid = tid >> 6;
    int wm = (wid & 1) * 128, wn = (wid >> 1) * 64;

    const u16* ga[4]; const u16* gbp[4]; int loff[4];
#pragma unroll
    for (int i = 0; i < 4; ++i) {
        int cidx = wid * 256 + i * 64 + lane;
        int row = cidx >> 3;
        int cg  = (cidx & 7) ^ (row & 7);
        int ra  = (row < nv) ? row : 0;
        ga[i]  = H + (size_t)(gb + ra) * DFF + cg * 8;
        gbp[i] = w2t + ((size_t)le * DIM + (size_t)nt * BN + row) * DFF + cg * 8;
        loff[i] = wid * 2048 + i * 512;
    }

    f32x4 acc[8][4];
#pragma unroll
    for (int i = 0; i < 8; ++i)
#pragma unroll
        for (int j = 0; j < 4; ++j) acc[i][j] = (f32x4){0.f, 0.f, 0.f, 0.f};

#define STAGE2(buf, kk)                                                         \
    do {                                                                        \
        _Pragma("unroll")                                                       \
        for (int i = 0; i < 4; ++i) {                                           \
            GLL16(ga[i] + (kk), &As[buf][loff[i]]);                             \
            GLL16(gbp[i] + (kk), &Bs[buf][loff[i]]);                            \
        }                                                                       \
    } while (0)

#define COMPUTE2(buf)                                                           \
    do {                                                                        \
        _Pragma("unroll")                                                       \
        for (int ks = 0; ks < 2; ++ks) {                                        \
            int kc = ks * 4 + (lane >> 4);                                      \
            bf16x8 af[8], bfr[4];                                               \
            _Pragma("unroll")                                                   \
            for (int mi = 0; mi < 8; ++mi) {                                    \
                int r = wm + mi * 16 + (lane & 15);                             \
                af[mi] = *(const bf16x8*)&As[buf][(r * 8 + (kc ^ (r & 7))) * 8];\
            }                                                                   \
            _Pragma("unroll")                                                   \
            for (int ni = 0; ni < 4; ++ni) {                                    \
                int r = wn + ni * 16 + (lane & 15);                             \
                bfr[ni] = *(const bf16x8*)&Bs[buf][(r * 8 + (kc ^ (r & 7))) * 8];\
            }                                                                   \
            _Pragma("unroll")                                                   \
            for (int mi = 0; mi < 8; ++mi)                                      \
                _Pragma("unroll")                                               \
                for (int ni = 0; ni < 4; ++ni)                                  \
                    acc[mi][ni] = __builtin_amdgcn_mfma_f32_16x16x32_bf16(      \
                        af[mi], bfr[ni], acc[mi][ni], 0, 0, 0);                 \
        }                                                                       \
    } while (0)

    int kbeg = ksp * (DFF / KS2);
    STAGE2(0, kbeg);
    int cur = 0;
    for (int t = 0; t < NIT2 - 1; ++t) {
        STAGE2(cur ^ 1, kbeg + (t + 1) * BK);
        asm volatile("s_waitcnt vmcnt(8)" ::: "memory");
        __builtin_amdgcn_s_barrier();
        __builtin_amdgcn_sched_barrier(0);
        COMPUTE2(cur);
        __builtin_amdgcn_s_barrier();
        cur ^= 1;
    }
    asm volatile("s_waitcnt vmcnt(0)" ::: "memory");
    __builtin_amdgcn_s_barrier();
    __builtin_amdgcn_sched_barrier(0);
    COMPUTE2(cur);

#pragma unroll
    for (int mi = 0; mi < 8; ++mi) {
#pragma unroll
        for (int r = 0; r < 4; ++r) {
            int row = wm + mi * 16 + (lane >> 4) * 4 + r;
            if (row < nv) {
                int gslot = gb + row;
                int t = tlist[gslot];
                float w = wlist[gslot];
                size_t yo = (size_t)t * DIM + nt * BN + wn + (lane & 15);
#pragma unroll
                for (int ni = 0; ni < 4; ++ni)
                    atomicAdd(&y[yo + ni * 16], w * acc[mi][ni][r]);
            }
        }
    }
#undef STAGE2
#undef COMPUTE2
}

extern "C" void kernel_launch(void* const* d_in, const int* in_sizes, int n_in,
                              void* d_out, int out_size, void* d_ws, size_t ws_size,
                              hipStream_t stream) {
    const float* x  = (const float*)d_in[0];   // [N, D] fp32
    const float* gw = (const float*)d_in[1];   // [D, E] fp32
    const float* w1 = (const float*)d_in[2];   // [E, D, DFF] fp32
    const float* w2 = (const float*)d_in[3];   // [E, DFF, D] fp32
    float* y = (float*)d_out;                  // [N, D] fp32

    char* ws = (char*)d_ws;
    int*   tok_e  = (int*)(ws + TOKE_OFF);
    float* tok_w  = (float*)(ws + TOKW_OFF);
    int*   tlist  = (int*)(ws + TLIST_OFF);
    float* wlist  = (float*)(ws + WLIST_OFF);
    int*   counts = (int*)(ws + COUNTS_OFF);
    int*   basep  = (int*)(ws + BASEP_OFF);
    int*   cursor = (int*)(ws + CURSOR_OFF);
    int*   qtab   = (int*)(ws + QTAB_OFF);
    u16*   xb     = (u16*)(ws + XB_OFF);
    u16*   H      = (u16*)(ws + H_OFF);
    u16*   wt     = (u16*)(ws + WT_OFF);

    hipMemsetAsync(counts, 0, 32, stream);
    hipMemsetAsync(y, 0, (size_t)N_TOK * DIM * sizeof(float), stream);
    gate_kernel<<<N_TOK / 32, 256, 0, stream>>>(x, gw, xb, tok_e, tok_w, counts);
    scan_kernel<<<1, 64, 0, stream>>>(counts, basep, cursor, qtab);
    assign_kernel<<<N_TOK / 256, 256, 0, stream>>>(tok_e, tok_w, basep, cursor, tlist, wlist);
    for (int q = 0; q < NE / QE; ++q) {
        convtrans<<<dim3(DFF / 32, DIM / 32, QE), 256, 0, stream>>>(
            w1 + (size_t)q * QE * DIM * DFF, wt, DIM, DFF);
        gemm1_silu<<<1152, 512, 0, stream>>>(xb, wt, tlist, counts, basep, qtab, H, q * QE);
    }
    for (int q = 0; q < NE / QE; ++q) {
        convtrans<<<dim3(DIM / 32, DFF / 32, QE), 256, 0, stream>>>(
            w2 + (size_t)q * QE * DFF * DIM, wt, DFF, DIM);
        gemm2_combine<<<576, 512, 0, stream>>>(H, wt, tlist, wlist, counts, basep, qtab,
                                               y, q * QE);
    }
}

// Round 4
// 994.561 us; speedup vs baseline: 1.0148x; 1.0148x over previous
//
#include <hip/hip_runtime.h>

// MoE top-2: N=8192, D=1024, E=8, DFF=4096. FP32 storage, bf16 MFMA internals.
// R3 lesson: GEMMs are LATENCY-bound (halving bytes made it slower; per-pipeline
//   staging ~4-5 B/cyc/CU). 256^2 => 1 block/CU structurally (128 acc VGPR).
// R4: deep pipeline at 256^2: BK=32, 4 LDS buffers (128 KiB), prefetch depth 3
//   K-tiles, counted vmcnt(8) boundaries, 2 phases/K-tile {GLL issue -> ds_read
//   -> setprio+16 MFMA}, 1 barrier/tile. Device-side bijective XCD swizzle over
//   the RUNTIME active-block count (R3 parked actives on half the XCDs).
//   KS2=4 (NT=32 both gemms). Merged single-dispatch GEMMs when ws allows.

#define N_TOK 8192
#define DIM   1024
#define NE    8
#define DFF   4096
#define BM 256
#define BN 256
#define KS2 4
#define NT 32              // K-tiles per block: gemm1 DIM/32, gemm2 DFF/KS2/32

typedef unsigned short u16;
typedef short bf16x8 __attribute__((ext_vector_type(8)));
typedef float f32x4  __attribute__((ext_vector_type(4)));

// ---- workspace offsets (bytes) ----
#define TOKE_OFF   0u
#define TOKW_OFF   32768u
#define TLIST_OFF  65536u
#define WLIST_OFF  131072u
#define COUNTS_OFF 196608u
#define BASEP_OFF  196672u
#define CURSOR_OFF 196736u
#define QTAB_OFF   197120u       // int[2][80] m-tile tables
#define XB_OFF     1048576u      // 16 MiB bf16 x
#define H_OFF      17825792u     // 128 MiB bf16 H
#define WT_OFF     152043520u    // 32 MiB (per-quad) or 64 MiB (merged) wt
#define WS_MERGED  219152384ull  // WT_OFF + 64 MiB

__device__ __forceinline__ u16 f2bf(float f) {
    unsigned u = __float_as_uint(f);
    unsigned r = u + 0x7FFFu + ((u >> 16) & 1u);   // RNE
    return (u16)(r >> 16);
}

#define GLL16(g, l)                                                             \
    __builtin_amdgcn_global_load_lds(                                           \
        (const __attribute__((address_space(1))) unsigned int*)(g),             \
        (__attribute__((address_space(3))) unsigned int*)(l), 16, 0, 0)

// LDS fragment index (u16 units) for BK=32 swizzled tile: rows paired into
// 128-B groups of 8x16B slots, slot = ((r&1)<<2 | kc) ^ (rgrp&7).
#define LIDX(r, kc) ((((r) >> 1) << 6) + ((((((r) & 1) << 2) | (kc)) ^ (((r) >> 1) & 7)) << 3))

// ------ convert+transpose: in fp32 [z][R][C] -> out bf16 [z][C][R] --------
__global__ __launch_bounds__(256) void convtrans(
        const float* __restrict__ in, u16* __restrict__ out, int R, int C) {
    __shared__ float t[32][33];
    int z = blockIdx.z;
    const float* src = in  + (size_t)z * R * C;
    u16*         dst = out + (size_t)z * R * C;
    int c0 = blockIdx.x * 32, r0 = blockIdx.y * 32;
    int tx = threadIdx.x & 7, ty = threadIdx.x >> 3;   // 8 x 32
    float4 v = *(const float4*)&src[(size_t)(r0 + ty) * C + c0 + tx * 4];
    t[tx * 4 + 0][ty] = v.x;  t[tx * 4 + 1][ty] = v.y;
    t[tx * 4 + 2][ty] = v.z;  t[tx * 4 + 3][ty] = v.w;
    __syncthreads();
    ushort4 o;
    o.x = f2bf(t[ty][tx * 4 + 0]);  o.y = f2bf(t[ty][tx * 4 + 1]);
    o.z = f2bf(t[ty][tx * 4 + 2]);  o.w = f2bf(t[ty][tx * 4 + 3]);
    *(ushort4*)&dst[(size_t)(c0 + ty) * R + r0 + tx * 4] = o;
}

// ------ gate ------
__global__ __launch_bounds__(256) void gate_kernel(
        const float* __restrict__ x, const float* __restrict__ gw,
        u16* __restrict__ xb, int* __restrict__ tok_e, float* __restrict__ tok_w,
        int* __restrict__ counts) {
    __shared__ float gsm[NE * DIM];
    __shared__ int hcnt[NE];
    int tid = threadIdx.x;
    if (tid < NE) hcnt[tid] = 0;
    for (int i = tid; i < NE * DIM; i += 256) {
        int d = i >> 3, e = i & 7;
        gsm[e * DIM + d] = gw[i];
    }
    __syncthreads();
    int lane = tid & 63, wid = tid >> 6;
    int t0 = blockIdx.x * 32 + wid * 8;
    for (int tt = 0; tt < 8; ++tt) {
        int t = t0 + tt;
        const float4* xr  = (const float4*)(x  + (size_t)t * DIM);
        ushort4*      xbr = (ushort4*)(xb + (size_t)t * DIM);
        float acc[NE];
#pragma unroll
        for (int e = 0; e < NE; ++e) acc[e] = 0.f;
#pragma unroll
        for (int j = 0; j < 4; ++j) {
            float4 xv = xr[j * 64 + lane];
            ushort4 o;
            o.x = f2bf(xv.x); o.y = f2bf(xv.y); o.z = f2bf(xv.z); o.w = f2bf(xv.w);
            xbr[j * 64 + lane] = o;
            int dbase = (j * 64 + lane) * 4;
#pragma unroll
            for (int e = 0; e < NE; ++e) {
                float4 g = *(const float4*)&gsm[e * DIM + dbase];
                acc[e] += xv.x * g.x + xv.y * g.y + xv.z * g.z + xv.w * g.w;
            }
        }
#pragma unroll
        for (int off = 32; off > 0; off >>= 1) {
#pragma unroll
            for (int e = 0; e < NE; ++e) acc[e] += __shfl_xor(acc[e], off, 64);
        }
        if (lane == 0) {
            int a = 0;
#pragma unroll
            for (int e = 1; e < NE; ++e) if (acc[e] > acc[a]) a = e;
            int b = (a == 0) ? 1 : 0;
#pragma unroll
            for (int e = 0; e < NE; ++e) if (e != a && acc[e] > acc[b]) b = e;
            float wa = 1.f / (1.f + __expf(acc[b] - acc[a]));
            tok_e[t] = (a << 3) | b;
            tok_w[t] = wa;
            atomicAdd(&hcnt[a], 1);
            atomicAdd(&hcnt[b], 1);
        }
    }
    __syncthreads();
    if (tid < NE) atomicAdd(&counts[tid], hcnt[tid]);
}

// scan + m-tile tables per expert-group (eper = 4 or 8)
__global__ void scan_kernel(const int* __restrict__ counts, int* __restrict__ basep,
                            int* __restrict__ cursor, int* __restrict__ qtab, int eper) {
    if (threadIdx.x == 0) {
        int s = 0;
        for (int e = 0; e < NE; ++e) { basep[e] = s; s += counts[e]; cursor[e] = 0; }
        int ngrp = NE / eper;
        for (int qq = 0; qq < ngrp; ++qq) {
            int n = 0;
            for (int le = 0; le < eper; ++le) {
                int e = qq * eper + le;
                int c = counts[e];
                for (int r0 = 0; r0 < c; r0 += BM) { qtab[qq * 80 + 1 + n] = (e << 20) | r0; ++n; }
            }
            qtab[qq * 80] = n;
        }
    }
}

__global__ void assign_kernel(const int* __restrict__ tok_e, const float* __restrict__ tok_w,
                              const int* __restrict__ basep, int* __restrict__ cursor,
                              int* __restrict__ tlist, float* __restrict__ wlist) {
    int t = blockIdx.x * 256 + threadIdx.x;
    if (t >= N_TOK) return;
    int ee = tok_e[t];
    int a = ee >> 3, b = ee & 7;
    float wa = tok_w[t];
    int pa = atomicAdd(&cursor[a], 1);
    int sa = basep[a] + pa;
    tlist[sa] = t;  wlist[sa] = wa;
    int pb = atomicAdd(&cursor[b], 1);
    int sb = basep[b] + pb;
    tlist[sb] = t;  wlist[sb] = 1.f - wa;
}

// device-side bijective XCD chunk swizzle over runtime active count (m204)
__device__ __forceinline__ int swz_lid(int bx, int na) {
    if (bx >= na) return bx;
    int x = bx & 7, idx = bx >> 3, q = na >> 3, r2 = na & 7;
    return (x < r2 ? x * (q + 1) : r2 * (q + 1) + (x - r2) * q) + idx;
}

// ---------------- gemm1+SiLU: H[slot][f] = silu(xb[tok] @ w1[e]) ----------
__global__ __launch_bounds__(512, 2) void gemm1_silu(
        const u16* __restrict__ xb, const u16* __restrict__ w1t,
        const int* __restrict__ tlist, const int* __restrict__ counts,
        const int* __restrict__ basep, const int* __restrict__ qtab,
        u16* __restrict__ H, int ebase, int tabsel) {
    const int* tab = qtab + tabsel * 80;
    int na = tab[0] * 16;
    int lid = swz_lid(blockIdx.x, na);
    int g = lid >> 4, nt = lid & 15;
    if (g >= tab[0]) return;
    int pk = tab[1 + g];
    int e = pk >> 20, row0 = pk & 0xFFFFF;
    int le = e - ebase;
    int cnt = counts[e];
    int nv = cnt - row0; if (nv > BM) nv = BM;
    int gb = basep[e] + row0;

    __shared__ __align__(16) u16 As[4][8192];   // 4 bufs x 16 KiB (256x32 bf16)
    __shared__ __align__(16) u16 Bs[4][8192];

    int tid = threadIdx.x, lane = tid & 63, wid = tid >> 6;
    int wm = (wid & 1) * 128, wn = (wid >> 1) * 64;

    // staging: tile-pair = 2048 chunks of 16 B; wave stages 2 A + 2 B chunks
    // per lane. LDS dest linear; global source pre-swizzled (inverse of LIDX).
    const u16* ga[2]; const u16* gbp[2]; int loff[2];
#pragma unroll
    for (int i = 0; i < 2; ++i) {
        int c = (wid * 2 + i) * 64 + lane;      // 0..1023
        int rg = c >> 3, sl = (c & 7) ^ (rg & 7);
        int r = (rg << 1) | (sl >> 2), cg = sl & 3;
        int ra = (r < nv) ? r : 0;
        ga[i]  = xb + (size_t)tlist[gb + ra] * DIM + cg * 8;
        gbp[i] = w1t + ((size_t)le * DFF + (size_t)nt * BN + r) * DIM + cg * 8;
        loff[i] = (wid * 2 + i) * 512;          // u16 units
    }

    f32x4 acc[8][4];
#pragma unroll
    for (int i = 0; i < 8; ++i)
#pragma unroll
        for (int j = 0; j < 4; ++j) acc[i][j] = (f32x4){0.f, 0.f, 0.f, 0.f};

#define STG_A(b, kk) do { GLL16(ga[0] + (kk), &As[b][loff[0]]);                 \
                          GLL16(ga[1] + (kk), &As[b][loff[1]]); } while (0)
#define STG_B(b, kk) do { GLL16(gbp[0] + (kk), &Bs[b][loff[0]]);                \
                          GLL16(gbp[1] + (kk), &Bs[b][loff[1]]); } while (0)

    // prologue: stage tiles 0..2 (12 loads), wait tile 0 (vmcnt 8), barrier
    STG_A(0, 0);  STG_B(0, 0);
    STG_A(1, 32); STG_B(1, 32);
    STG_A(2, 64); STG_B(2, 64);
    asm volatile("s_waitcnt vmcnt(8)" ::: "memory");
    __builtin_amdgcn_s_barrier();
    asm volatile("" ::: "memory");
    __builtin_amdgcn_sched_barrier(0);

    int kc = lane >> 4, l15 = lane & 15;
    for (int t = 0; t < NT; ++t) {
        int b = t & 3, pf = (t + 3) & 3;
        int kk = (t + 3) * 32;
        // phase 0: issue A prefetch; frags (rows wm..wm+63 + B); 16 MFMA
        if (t + 3 < NT) STG_A(pf, kk);
        bf16x8 a0[4], b0[4];
#pragma unroll
        for (int mi = 0; mi < 4; ++mi)
            a0[mi] = *(const bf16x8*)&As[b][LIDX(wm + mi * 16 + l15, kc)];
#pragma unroll
        for (int ni = 0; ni < 4; ++ni)
            b0[ni] = *(const bf16x8*)&Bs[b][LIDX(wn + ni * 16 + l15, kc)];
        __builtin_amdgcn_s_setprio(1);
#pragma unroll
        for (int mi = 0; mi < 4; ++mi)
#pragma unroll
            for (int ni = 0; ni < 4; ++ni)
                acc[mi][ni] = __builtin_amdgcn_mfma_f32_16x16x32_bf16(
                    a0[mi], b0[ni], acc[mi][ni], 0, 0, 0);
        __builtin_amdgcn_s_setprio(0);
        // phase 1: issue B prefetch; frags rows wm+64..wm+127; 16 MFMA
        if (t + 3 < NT) STG_B(pf, kk);
        bf16x8 a1[4];
#pragma unroll
        for (int mi = 0; mi < 4; ++mi)
            a1[mi] = *(const bf16x8*)&As[b][LIDX(wm + 64 + mi * 16 + l15, kc)];
        __builtin_amdgcn_s_setprio(1);
#pragma unroll
        for (int mi = 0; mi < 4; ++mi)
#pragma unroll
            for (int ni = 0; ni < 4; ++ni)
                acc[mi + 4][ni] = __builtin_amdgcn_mfma_f32_16x16x32_bf16(
                    a1[mi], b0[ni], acc[mi + 4][ni], 0, 0, 0);
        __builtin_amdgcn_s_setprio(0);
        // boundary: wait until tile t+1 landed (counted, never over-drain)
        if (t < NT - 1) {
            if (t < NT - 3)       asm volatile("s_waitcnt vmcnt(8)" ::: "memory");
            else if (t == NT - 3) asm volatile("s_waitcnt vmcnt(4)" ::: "memory");
            else                  asm volatile("s_waitcnt vmcnt(0)" ::: "memory");
            __builtin_amdgcn_s_barrier();
            asm volatile("" ::: "memory");
            __builtin_amdgcn_sched_barrier(0);
        }
    }
#undef STG_A
#undef STG_B

    // epilogue: SiLU -> bf16 -> H. C layout: col=lane&15, row=(lane>>4)*4+r.
#pragma unroll
    for (int mi = 0; mi < 8; ++mi) {
#pragma unroll
        for (int r = 0; r < 4; ++r) {
            int row = wm + mi * 16 + (lane >> 4) * 4 + r;
            if (row < nv) {
                size_t ho = (size_t)(gb + row) * DFF + nt * BN + wn + l15;
#pragma unroll
                for (int ni = 0; ni < 4; ++ni) {
                    float v = acc[mi][ni][r];
                    H[ho + ni * 16] = f2bf(v / (1.f + __expf(-v)));
                }
            }
        }
    }
}

// ---- gemm2 + combine: y[tok][d] += w * (H[slot] @ w2[e]), fp32 atomics ----
__global__ __launch_bounds__(512, 2) void gemm2_combine(
        const u16* __restrict__ H, const u16* __restrict__ w2t,
        const int* __restrict__ tlist, const float* __restrict__ wlist,
        const int* __restrict__ counts, const int* __restrict__ basep,
        const int* __restrict__ qtab, float* __restrict__ y, int ebase, int tabsel) {
    const int* tab = qtab + tabsel * 80;
    int na = tab[0] * 16;
    int lid = swz_lid(blockIdx.x, na);
    int g = lid >> 4, nt = (lid >> 2) & 3, ksp = lid & 3;
    if (g >= tab[0]) return;
    int pk = tab[1 + g];
    int e = pk >> 20, row0 = pk & 0xFFFFF;
    int le = e - ebase;
    int cnt = counts[e];
    int nv = cnt - row0; if (nv > BM) nv = BM;
    int gb = basep[e] + row0;

    __shared__ __align__(16) u16 As[4][8192];
    __shared__ __align__(16) u16 Bs[4][8192];

    int tid = threadIdx.x, lane = tid & 63, wid = tid >> 6;
    int wm = (wid & 1) * 128, wn = (wid >> 1) * 64;

    int kbase = ksp * (DFF / KS2);   // 1024-col K slice

    const u16* ga[2]; const u16* gbp[2]; int loff[2];
#pragma unroll
    for (int i = 0; i < 2; ++i) {
        int c = (wid * 2 + i) * 64 + lane;
        int rg = c >> 3, sl = (c & 7) ^ (rg & 7);
        int r = (rg << 1) | (sl >> 2), cg = sl & 3;
        int ra = (r < nv) ? r : 0;
        ga[i]  = H + (size_t)(gb + ra) * DFF + kbase + cg * 8;
        gbp[i] = w2t + ((size_t)le * DIM + (size_t)nt * BN + r) * DFF + kbase + cg * 8;
        loff[i] = (wid * 2 + i) * 512;
    }

    f32x4 acc[8][4];
#pragma unroll
    for (int i = 0; i < 8; ++i)
#pragma unroll
        for (int j = 0; j < 4; ++j) acc[i][j] = (f32x4){0.f, 0.f, 0.f, 0.f};

#define STG_A(b, kk) do { GLL16(ga[0] + (kk), &As[b][loff[0]]);                 \
                          GLL16(ga[1] + (kk), &As[b][loff[1]]); } while (0)
#define STG_B(b, kk) do { GLL16(gbp[0] + (kk), &Bs[b][loff[0]]);                \
                          GLL16(gbp[1] + (kk), &Bs[b][loff[1]]); } while (0)

    STG_A(0, 0);  STG_B(0, 0);
    STG_A(1, 32); STG_B(1, 32);
    STG_A(2, 64); STG_B(2, 64);
    asm volatile("s_waitcnt vmcnt(8)" ::: "memory");
    __builtin_amdgcn_s_barrier();
    asm volatile("" ::: "memory");
    __builtin_amdgcn_sched_barrier(0);

    int kc = lane >> 4, l15 = lane & 15;
    for (int t = 0; t < NT; ++t) {
        int b = t & 3, pf = (t + 3) & 3;
        int kk = (t + 3) * 32;
        if (t + 3 < NT) STG_A(pf, kk);
        bf16x8 a0[4], b0[4];
#pragma unroll
        for (int mi = 0; mi < 4; ++mi)
            a0[mi] = *(const bf16x8*)&As[b][LIDX(wm + mi * 16 + l15, kc)];
#pragma unroll
        for (int ni = 0; ni < 4; ++ni)
            b0[ni] = *(const bf16x8*)&Bs[b][LIDX(wn + ni * 16 + l15, kc)];
        __builtin_amdgcn_s_setprio(1);
#pragma unroll
        for (int mi = 0; mi < 4; ++mi)
#pragma unroll
            for (int ni = 0; ni < 4; ++ni)
                acc[mi][ni] = __builtin_amdgcn_mfma_f32_16x16x32_bf16(
                    a0[mi], b0[ni], acc[mi][ni], 0, 0, 0);
        __builtin_amdgcn_s_setprio(0);
        if (t + 3 < NT) STG_B(pf, kk);
        bf16x8 a1[4];
#pragma unroll
        for (int mi = 0; mi < 4; ++mi)
            a1[mi] = *(const bf16x8*)&As[b][LIDX(wm + 64 + mi * 16 + l15, kc)];
        __builtin_amdgcn_s_setprio(1);
#pragma unroll
        for (int mi = 0; mi < 4; ++mi)
#pragma unroll
            for (int ni = 0; ni < 4; ++ni)
                acc[mi + 4][ni] = __builtin_amdgcn_mfma_f32_16x16x32_bf16(
                    a1[mi], b0[ni], acc[mi + 4][ni], 0, 0, 0);
        __builtin_amdgcn_s_setprio(0);
        if (t < NT - 1) {
            if (t < NT - 3)       asm volatile("s_waitcnt vmcnt(8)" ::: "memory");
            else if (t == NT - 3) asm volatile("s_waitcnt vmcnt(4)" ::: "memory");
            else                  asm volatile("s_waitcnt vmcnt(0)" ::: "memory");
            __builtin_amdgcn_s_barrier();
            asm volatile("" ::: "memory");
            __builtin_amdgcn_sched_barrier(0);
        }
    }
#undef STG_A
#undef STG_B

#pragma unroll
    for (int mi = 0; mi < 8; ++mi) {
#pragma unroll
        for (int r = 0; r < 4; ++r) {
            int row = wm + mi * 16 + (lane >> 4) * 4 + r;
            if (row < nv) {
                int gslot = gb + row;
                int t = tlist[gslot];
                float w = wlist[gslot];
                size_t yo = (size_t)t * DIM + nt * BN + wn + l15;
#pragma unroll
                for (int ni = 0; ni < 4; ++ni)
                    atomicAdd(&y[yo + ni * 16], w * acc[mi][ni][r]);
            }
        }
    }
}

extern "C" void kernel_launch(void* const* d_in, const int* in_sizes, int n_in,
                              void* d_out, int out_size, void* d_ws, size_t ws_size,
                              hipStream_t stream) {
    const float* x  = (const float*)d_in[0];
    const float* gw = (const float*)d_in[1];
    const float* w1 = (const float*)d_in[2];
    const float* w2 = (const float*)d_in[3];
    float* y = (float*)d_out;

    char* ws = (char*)d_ws;
    int*   tok_e  = (int*)(ws + TOKE_OFF);
    float* tok_w  = (float*)(ws + TOKW_OFF);
    int*   tlist  = (int*)(ws + TLIST_OFF);
    float* wlist  = (float*)(ws + WLIST_OFF);
    int*   counts = (int*)(ws + COUNTS_OFF);
    int*   basep  = (int*)(ws + BASEP_OFF);
    int*   cursor = (int*)(ws + CURSOR_OFF);
    int*   qtab   = (int*)(ws + QTAB_OFF);
    u16*   xb     = (u16*)(ws + XB_OFF);
    u16*   H      = (u16*)(ws + H_OFF);
    u16*   wt     = (u16*)(ws + WT_OFF);

    // merged mode: one dispatch per GEMM with all 8 experts' transposed weights
    // (needs 64 MiB wt); else 2 quads of 4 experts (32 MiB wt).
    int nq = (ws_size >= WS_MERGED) ? 1 : 2;
    int eper = NE / nq;

    hipMemsetAsync(counts, 0, 32, stream);
    hipMemsetAsync(y, 0, (size_t)N_TOK * DIM * sizeof(float), stream);
    gate_kernel<<<N_TOK / 32, 256, 0, stream>>>(x, gw, xb, tok_e, tok_w, counts);
    scan_kernel<<<1, 64, 0, stream>>>(counts, basep, cursor, qtab, eper);
    assign_kernel<<<N_TOK / 256, 256, 0, stream>>>(tok_e, tok_w, basep, cursor, tlist, wlist);
    for (int q = 0; q < nq; ++q) {
        convtrans<<<dim3(DFF / 32, DIM / 32, eper), 256, 0, stream>>>(
            w1 + (size_t)q * eper * DIM * DFF, wt, DIM, DFF);
        gemm1_silu<<<1152, 512, 0, stream>>>(xb, wt, tlist, counts, basep, qtab,
                                             H, q * eper, q);
    }
    for (int q = 0; q < nq; ++q) {
        convtrans<<<dim3(DIM / 32, DFF / 32, eper), 256, 0, stream>>>(
            w2 + (size_t)q * eper * DFF * DIM, wt, DFF, DIM);
        gemm2_combine<<<1152, 512, 0, stream>>>(H, wt, tlist, wlist, counts, basep, qtab,
                                                y, q * eper, q);
    }
}

// Round 5
// 853.316 us; speedup vs baseline: 1.1827x; 1.1655x over previous
//
#include <hip/hip_runtime.h>

// MoE top-2: N=8192, D=1024, E=8, DFF=4096. FP32 storage, bf16 MFMA internals.
// R4 lesson: MfmaUtil ~14% invariant under occupancy/split-K/tile/pipe-depth.
//   Staging rate fits "~1 outstanding global_load_lds per wave": rate =
//   waves/CU x 1KB / latency. LDS-DMA has no per-wave MLP; depth is useless.
// R5: gemm2 staging -> REG-STAGED (global loads to VGPR, swizzled ds_write,
//   issue-early/write-late, 2 reg-sets, 2-tile prefetch, raw s_barrier with
//   compiler-tracked per-register vmcnt). Global reads now linear/coalesced;
//   swizzle applied at ds_write; frag reads unchanged. gemm1 kept at proven
//   R2 structure (single-var experiment), both gemms merged single-dispatch
//   via qtab + device bijective XCD swizzle.

#define N_TOK 8192
#define DIM   1024
#define NE    8
#define DFF   4096
#define BM 128
#define BN 128
#define BK 64
#define KS2 2
#define NT2 (DFF / KS2 / BK)   // 16? no: 4096/2/64 = 32 K-steps gemm2
#define NT1 (DIM / BK)         // 16 K-steps gemm1
#define QSTR 160               // qtab stride (1 count + <=136 entries)

typedef unsigned short u16;
typedef short bf16x8 __attribute__((ext_vector_type(8)));
typedef float f32x4  __attribute__((ext_vector_type(4)));

// ---- workspace offsets (bytes) ----
#define TOKE_OFF   0u
#define TOKW_OFF   32768u
#define TLIST_OFF  65536u
#define WLIST_OFF  131072u
#define COUNTS_OFF 196608u
#define BASEP_OFF  196672u
#define CURSOR_OFF 196736u
#define QTAB_OFF   197120u       // int[2][QSTR]
#define XB_OFF     1048576u      // 16 MiB bf16 x
#define H_OFF      17825792u     // 128 MiB bf16 H
#define WT_OFF     152043520u    // 32 MiB (per-quad) or 64 MiB (merged) wt
#define WS_MERGED  219152384ull

__device__ __forceinline__ u16 f2bf(float f) {
    unsigned u = __float_as_uint(f);
    unsigned r = u + 0x7FFFu + ((u >> 16) & 1u);   // RNE
    return (u16)(r >> 16);
}

#define GLL16(g, l)                                                             \
    __builtin_amdgcn_global_load_lds(                                           \
        (const __attribute__((address_space(1))) unsigned int*)(g),             \
        (__attribute__((address_space(3))) unsigned int*)(l), 16, 0, 0)

// ------ convert+transpose: in fp32 [z][R][C] -> out bf16 [z][C][R] --------
__global__ __launch_bounds__(256) void convtrans(
        const float* __restrict__ in, u16* __restrict__ out, int R, int C) {
    __shared__ float t[32][33];
    int z = blockIdx.z;
    const float* src = in  + (size_t)z * R * C;
    u16*         dst = out + (size_t)z * R * C;
    int c0 = blockIdx.x * 32, r0 = blockIdx.y * 32;
    int tx = threadIdx.x & 7, ty = threadIdx.x >> 3;   // 8 x 32
    float4 v = *(const float4*)&src[(size_t)(r0 + ty) * C + c0 + tx * 4];
    t[tx * 4 + 0][ty] = v.x;  t[tx * 4 + 1][ty] = v.y;
    t[tx * 4 + 2][ty] = v.z;  t[tx * 4 + 3][ty] = v.w;
    __syncthreads();
    ushort4 o;
    o.x = f2bf(t[ty][tx * 4 + 0]);  o.y = f2bf(t[ty][tx * 4 + 1]);
    o.z = f2bf(t[ty][tx * 4 + 2]);  o.w = f2bf(t[ty][tx * 4 + 3]);
    *(ushort4*)&dst[(size_t)(c0 + ty) * R + r0 + tx * 4] = o;
}

// ------ gate ------
__global__ __launch_bounds__(256) void gate_kernel(
        const float* __restrict__ x, const float* __restrict__ gw,
        u16* __restrict__ xb, int* __restrict__ tok_e, float* __restrict__ tok_w,
        int* __restrict__ counts) {
    __shared__ float gsm[NE * DIM];
    __shared__ int hcnt[NE];
    int tid = threadIdx.x;
    if (tid < NE) hcnt[tid] = 0;
    for (int i = tid; i < NE * DIM; i += 256) {
        int d = i >> 3, e = i & 7;
        gsm[e * DIM + d] = gw[i];
    }
    __syncthreads();
    int lane = tid & 63, wid = tid >> 6;
    int t0 = blockIdx.x * 32 + wid * 8;
    for (int tt = 0; tt < 8; ++tt) {
        int t = t0 + tt;
        const float4* xr  = (const float4*)(x  + (size_t)t * DIM);
        ushort4*      xbr = (ushort4*)(xb + (size_t)t * DIM);
        float acc[NE];
#pragma unroll
        for (int e = 0; e < NE; ++e) acc[e] = 0.f;
#pragma unroll
        for (int j = 0; j < 4; ++j) {
            float4 xv = xr[j * 64 + lane];
            ushort4 o;
            o.x = f2bf(xv.x); o.y = f2bf(xv.y); o.z = f2bf(xv.z); o.w = f2bf(xv.w);
            xbr[j * 64 + lane] = o;
            int dbase = (j * 64 + lane) * 4;
#pragma unroll
            for (int e = 0; e < NE; ++e) {
                float4 g = *(const float4*)&gsm[e * DIM + dbase];
                acc[e] += xv.x * g.x + xv.y * g.y + xv.z * g.z + xv.w * g.w;
            }
        }
#pragma unroll
        for (int off = 32; off > 0; off >>= 1) {
#pragma unroll
            for (int e = 0; e < NE; ++e) acc[e] += __shfl_xor(acc[e], off, 64);
        }
        if (lane == 0) {
            int a = 0;
#pragma unroll
            for (int e = 1; e < NE; ++e) if (acc[e] > acc[a]) a = e;
            int b = (a == 0) ? 1 : 0;
#pragma unroll
            for (int e = 0; e < NE; ++e) if (e != a && acc[e] > acc[b]) b = e;
            float wa = 1.f / (1.f + __expf(acc[b] - acc[a]));
            tok_e[t] = (a << 3) | b;
            tok_w[t] = wa;
            atomicAdd(&hcnt[a], 1);
            atomicAdd(&hcnt[b], 1);
        }
    }
    __syncthreads();
    if (tid < NE) atomicAdd(&counts[tid], hcnt[tid]);
}

// scan + per-group m-tile tables (BM=128 tiles)
__global__ void scan_kernel(const int* __restrict__ counts, int* __restrict__ basep,
                            int* __restrict__ cursor, int* __restrict__ qtab, int eper) {
    if (threadIdx.x == 0) {
        int s = 0;
        for (int e = 0; e < NE; ++e) { basep[e] = s; s += counts[e]; cursor[e] = 0; }
        int ngrp = NE / eper;
        for (int qq = 0; qq < ngrp; ++qq) {
            int n = 0;
            for (int le = 0; le < eper; ++le) {
                int e = qq * eper + le;
                int c = counts[e];
                for (int r0 = 0; r0 < c; r0 += BM) { qtab[qq * QSTR + 1 + n] = (e << 20) | r0; ++n; }
            }
            qtab[qq * QSTR] = n;
        }
    }
}

__global__ void assign_kernel(const int* __restrict__ tok_e, const float* __restrict__ tok_w,
                              const int* __restrict__ basep, int* __restrict__ cursor,
                              int* __restrict__ tlist, float* __restrict__ wlist) {
    int t = blockIdx.x * 256 + threadIdx.x;
    if (t >= N_TOK) return;
    int ee = tok_e[t];
    int a = ee >> 3, b = ee & 7;
    float wa = tok_w[t];
    int pa = atomicAdd(&cursor[a], 1);
    int sa = basep[a] + pa;
    tlist[sa] = t;  wlist[sa] = wa;
    int pb = atomicAdd(&cursor[b], 1);
    int sb = basep[b] + pb;
    tlist[sb] = t;  wlist[sb] = 1.f - wa;
}

// device-side bijective XCD chunk swizzle over runtime active count (m204)
__device__ __forceinline__ int swz_lid(int bx, int na) {
    if (bx >= na) return bx;
    int x = bx & 7, idx = bx >> 3, q = na >> 3, r2 = na & 7;
    return (x < r2 ? x * (q + 1) : r2 * (q + 1) + (x - r2) * q) + idx;
}

// ---------------- gemm1+SiLU (R2-proven structure: 128^2, 1-buf, GLL) -------
__global__ __launch_bounds__(256) void gemm1_silu(
        const u16* __restrict__ xb, const u16* __restrict__ w1t,
        const int* __restrict__ tlist, const int* __restrict__ counts,
        const int* __restrict__ basep, const int* __restrict__ qtab,
        u16* __restrict__ H, int ebase, int tabsel) {
    const int* tab = qtab + tabsel * QSTR;
    int na = tab[0] * 32;
    int lid = swz_lid(blockIdx.x, na);
    int g = lid >> 5, nt = lid & 31;
    if (g >= tab[0]) return;
    int pk = tab[1 + g];
    int e = pk >> 20, row0 = pk & 0xFFFFF;
    int le = e - ebase;
    int cnt = counts[e];
    int nv = cnt - row0; if (nv > BM) nv = BM;
    int gb = basep[e] + row0;

    __shared__ __align__(16) u16 As[BM * BK];   // 16 KiB each
    __shared__ __align__(16) u16 Bs[BN * BK];

    int tid = threadIdx.x;
    int lane = tid & 63, wid = tid >> 6;
    int wm = (wid & 1) * 64, wn = (wid >> 1) * 64;

    const u16* ga[4]; const u16* gbp[4]; int loff[4];
#pragma unroll
    for (int i = 0; i < 4; ++i) {
        int cidx = (wid * 4 + i) * 64 + lane;   // 0..1023
        int row = cidx >> 3;
        int cg  = (cidx & 7) ^ (row & 7);
        int ra  = (row < nv) ? row : 0;
        ga[i]  = xb + (size_t)tlist[gb + ra] * DIM + cg * 8;
        gbp[i] = w1t + ((size_t)le * DFF + (size_t)nt * BN + row) * DIM + cg * 8;
        loff[i] = (wid * 4 + i) * 512;
    }

    f32x4 acc[4][4];
#pragma unroll
    for (int i = 0; i < 4; ++i)
#pragma unroll
        for (int j = 0; j < 4; ++j) acc[i][j] = (f32x4){0.f, 0.f, 0.f, 0.f};

    for (int k0 = 0; k0 < DIM; k0 += BK) {
#pragma unroll
        for (int i = 0; i < 4; ++i) {
            GLL16(ga[i] + k0, &As[loff[i]]);
            GLL16(gbp[i] + k0, &Bs[loff[i]]);
        }
        __syncthreads();
#pragma unroll
        for (int ks = 0; ks < 2; ++ks) {
            int kc = ks * 4 + (lane >> 4);
            bf16x8 af[4], bfr[4];
#pragma unroll
            for (int mi = 0; mi < 4; ++mi) {
                int r = wm + mi * 16 + (lane & 15);
                af[mi] = *(const bf16x8*)&As[(r * 8 + (kc ^ (r & 7))) * 8];
            }
#pragma unroll
            for (int ni = 0; ni < 4; ++ni) {
                int r = wn + ni * 16 + (lane & 15);
                bfr[ni] = *(const bf16x8*)&Bs[(r * 8 + (kc ^ (r & 7))) * 8];
            }
#pragma unroll
            for (int mi = 0; mi < 4; ++mi)
#pragma unroll
                for (int ni = 0; ni < 4; ++ni)
                    acc[mi][ni] = __builtin_amdgcn_mfma_f32_16x16x32_bf16(
                        af[mi], bfr[ni], acc[mi][ni], 0, 0, 0);
        }
        __syncthreads();
    }
#pragma unroll
    for (int mi = 0; mi < 4; ++mi) {
#pragma unroll
        for (int r = 0; r < 4; ++r) {
            int row = wm + mi * 16 + (lane >> 4) * 4 + r;
            if (row < nv) {
                size_t ho = (size_t)(gb + row) * DFF + nt * BN + wn + (lane & 15);
#pragma unroll
                for (int ni = 0; ni < 4; ++ni) {
                    float v = acc[mi][ni][r];
                    H[ho + ni * 16] = f2bf(v / (1.f + __expf(-v)));
                }
            }
        }
    }
}

// ---- gemm2 + combine: REG-STAGED deep pipeline --------------------------
// 128^2 tile, BK=64, LDS dbuf 64 KiB (2 blocks/CU), 2 reg-sets, 2-tile-deep
// prefetch. Global reads linear (coalesced 128-B rows); XOR swizzle applied
// at ds_write; fragment reads unchanged. Raw s_barrier + lgkmcnt(0) only --
// vmcnt is compiler-tracked per register, so prefetch loads stay in flight.
__global__ __launch_bounds__(256, 2) void gemm2_combine(
        const u16* __restrict__ H, const u16* __restrict__ w2t,
        const int* __restrict__ tlist, const float* __restrict__ wlist,
        const int* __restrict__ counts, const int* __restrict__ basep,
        const int* __restrict__ qtab, float* __restrict__ y, int ebase, int tabsel) {
    const int* tab = qtab + tabsel * QSTR;
    int na = tab[0] * 8 * KS2;
    int lid = swz_lid(blockIdx.x, na);
    int g = lid >> 4, nt = (lid >> 1) & 7, ksp = lid & 1;
    if (g >= tab[0]) return;
    int pk = tab[1 + g];
    int e = pk >> 20, row0 = pk & 0xFFFFF;
    int le = e - ebase;
    int cnt = counts[e];
    int nv = cnt - row0; if (nv > BM) nv = BM;
    int gb = basep[e] + row0;
    int kbase = ksp * (DFF / KS2);

    __shared__ __align__(16) u16 As[2][BM * BK];   // 2 x 16 KiB
    __shared__ __align__(16) u16 Bs[2][BN * BK];

    int tid = threadIdx.x;
    int lane = tid & 63, wid = tid >> 6;
    int wm = (wid & 1) * 64, wn = (wid >> 1) * 64;

    // linear global addressing: chunk c = i*256+tid -> row=c>>3, j=c&7
    const u16* gA[4]; const u16* gB[4]; int woff[4];
#pragma unroll
    for (int i = 0; i < 4; ++i) {
        int c = i * 256 + tid;
        int row = c >> 3, j = c & 7;
        int ra = (row < nv) ? row : 0;
        gA[i] = H + (size_t)(gb + ra) * DFF + kbase + j * 8;
        gB[i] = w2t + ((size_t)le * DIM + (size_t)nt * BN + row) * DFF + kbase + j * 8;
        woff[i] = (row * 8 + (j ^ (row & 7))) * 8;   // u16 units, swizzled
    }

    f32x4 acc[4][4];
#pragma unroll
    for (int i = 0; i < 4; ++i)
#pragma unroll
        for (int j = 0; j < 4; ++j) acc[i][j] = (f32x4){0.f, 0.f, 0.f, 0.f};

    bf16x8 sA0[4], sB0[4], sA1[4], sB1[4];

#define LOADSET(sa, sb, kk)                                                     \
    do {                                                                        \
        _Pragma("unroll")                                                       \
        for (int i = 0; i < 4; ++i) {                                           \
            sa[i] = *(const bf16x8*)(gA[i] + (kk));                             \
            sb[i] = *(const bf16x8*)(gB[i] + (kk));                             \
        }                                                                       \
    } while (0)

#define WRITESET(sa, sb, buf)                                                   \
    do {                                                                        \
        _Pragma("unroll")                                                       \
        for (int i = 0; i < 4; ++i) {                                           \
            *(bf16x8*)&As[buf][woff[i]] = sa[i];                                \
            *(bf16x8*)&Bs[buf][woff[i]] = sb[i];                                \
        }                                                                       \
    } while (0)

#define COMPUTE2(buf)                                                           \
    do {                                                                        \
        _Pragma("unroll")                                                       \
        for (int ks = 0; ks < 2; ++ks) {                                        \
            int kc = ks * 4 + (lane >> 4);                                      \
            bf16x8 af[4], bfr[4];                                               \
            _Pragma("unroll")                                                   \
            for (int mi = 0; mi < 4; ++mi) {                                    \
                int r = wm + mi * 16 + (lane & 15);                             \
                af[mi] = *(const bf16x8*)&As[buf][(r * 8 + (kc ^ (r & 7))) * 8];\
            }                                                                   \
            _Pragma("unroll")                                                   \
            for (int ni = 0; ni < 4; ++ni) {                                    \
                int r = wn + ni * 16 + (lane & 15);                             \
                bfr[ni] = *(const bf16x8*)&Bs[buf][(r * 8 + (kc ^ (r & 7))) * 8];\
            }                                                                   \
            _Pragma("unroll")                                                   \
            for (int mi = 0; mi < 4; ++mi)                                      \
                _Pragma("unroll")                                               \
                for (int ni = 0; ni < 4; ++ni)                                  \
                    acc[mi][ni] = __builtin_amdgcn_mfma_f32_16x16x32_bf16(      \
                        af[mi], bfr[ni], acc[mi][ni], 0, 0, 0);                 \
        }                                                                       \
    } while (0)

#define LGKM0_BAR()                                                             \
    do {                                                                        \
        asm volatile("s_waitcnt lgkmcnt(0)" ::: "memory");                      \
        __builtin_amdgcn_s_barrier();                                           \
    } while (0)

    // prologue: buf0 <- tile0; set1 <- tile1 (flying); set0 <- tile2 (flying)
    LOADSET(sA0, sB0, 0);
    LOADSET(sA1, sB1, BK);
    WRITESET(sA0, sB0, 0);          // compiler waits vmcnt for set0 only
    LOADSET(sA0, sB0, 2 * BK);
    LGKM0_BAR();

    for (int t = 0; t < NT2; t += 2) {
        // even: compute tile t from buf0
        COMPUTE2(0);
        if (t + 1 < NT2) {
            WRITESET(sA1, sB1, 1);                       // tile t+1 -> buf1
            if (t + 3 < NT2) LOADSET(sA1, sB1, (t + 3) * BK);
        }
        LGKM0_BAR();
        if (t + 1 >= NT2) break;
        // odd: compute tile t+1 from buf1
        COMPUTE2(1);
        if (t + 2 < NT2) {
            WRITESET(sA0, sB0, 0);                       // tile t+2 -> buf0
            if (t + 4 < NT2) LOADSET(sA0, sB0, (t + 4) * BK);
        }
        LGKM0_BAR();
    }
#undef LOADSET
#undef WRITESET
#undef COMPUTE2
#undef LGKM0_BAR

#pragma unroll
    for (int mi = 0; mi < 4; ++mi) {
#pragma unroll
        for (int r = 0; r < 4; ++r) {
            int row = wm + mi * 16 + (lane >> 4) * 4 + r;
            if (row < nv) {
                int gslot = gb + row;
                int t = tlist[gslot];
                float w = wlist[gslot];
                size_t yo = (size_t)t * DIM + nt * BN + wn + (lane & 15);
#pragma unroll
                for (int ni = 0; ni < 4; ++ni)
                    atomicAdd(&y[yo + ni * 16], w * acc[mi][ni][r]);
            }
        }
    }
}

extern "C" void kernel_launch(void* const* d_in, const int* in_sizes, int n_in,
                              void* d_out, int out_size, void* d_ws, size_t ws_size,
                              hipStream_t stream) {
    const float* x  = (const float*)d_in[0];
    const float* gw = (const float*)d_in[1];
    const float* w1 = (const float*)d_in[2];
    const float* w2 = (const float*)d_in[3];
    float* y = (float*)d_out;

    char* ws = (char*)d_ws;
    int*   tok_e  = (int*)(ws + TOKE_OFF);
    float* tok_w  = (float*)(ws + TOKW_OFF);
    int*   tlist  = (int*)(ws + TLIST_OFF);
    float* wlist  = (float*)(ws + WLIST_OFF);
    int*   counts = (int*)(ws + COUNTS_OFF);
    int*   basep  = (int*)(ws + BASEP_OFF);
    int*   cursor = (int*)(ws + CURSOR_OFF);
    int*   qtab   = (int*)(ws + QTAB_OFF);
    u16*   xb     = (u16*)(ws + XB_OFF);
    u16*   H      = (u16*)(ws + H_OFF);
    u16*   wt     = (u16*)(ws + WT_OFF);

    int nq = (ws_size >= WS_MERGED) ? 1 : 2;
    int eper = NE / nq;

    hipMemsetAsync(counts, 0, 32, stream);
    hipMemsetAsync(y, 0, (size_t)N_TOK * DIM * sizeof(float), stream);
    gate_kernel<<<N_TOK / 32, 256, 0, stream>>>(x, gw, xb, tok_e, tok_w, counts);
    scan_kernel<<<1, 64, 0, stream>>>(counts, basep, cursor, qtab, eper);
    assign_kernel<<<N_TOK / 256, 256, 0, stream>>>(tok_e, tok_w, basep, cursor, tlist, wlist);
    for (int q = 0; q < nq; ++q) {
        convtrans<<<dim3(DFF / 32, DIM / 32, eper), 256, 0, stream>>>(
            w1 + (size_t)q * eper * DIM * DFF, wt, DIM, DFF);
        // worst-case tiles per group = 16384/128 + NE = 136 -> grid 136*32
        gemm1_silu<<<136 * 32, 256, 0, stream>>>(xb, wt, tlist, counts, basep, qtab,
                                                 H, q * eper, q);
    }
    for (int q = 0; q < nq; ++q) {
        convtrans<<<dim3(DIM / 32, DFF / 32, eper), 256, 0, stream>>>(
            w2 + (size_t)q * eper * DFF * DIM, wt, DFF, DIM);
        gemm2_combine<<<136 * 8 * KS2, 256, 0, stream>>>(H, wt, tlist, wlist, counts,
                                                         basep, qtab, y, q * eper, q);
    }
}